// Round 4
// baseline (644.596 us; speedup 1.0000x reference)
//
#include <hip/hip_runtime.h>

#define K1 3072
#define N1 1024
#define NCOL 50
#define BK 32
#define NSTEP (K1 / BK)   // 96
#define SAS 40            // staging row stride (bf16) = 80 B
#define SHS 136           // h / w2t row stride = 272 B

typedef float  f32x4  __attribute__((ext_vector_type(4)));
typedef short  short8 __attribute__((ext_vector_type(8)));

struct __align__(16) Smem {
  union {
    struct { short A[128 * SAS]; short BT[128 * SAS]; } s[2];  // 2 x 20.5 KB dbuf
    struct { short h[64 * SHS]; short w2t[64 * SHS]; } e;      // 34.8 KB epilogue
  } u;
};  // 41 KB

__device__ inline unsigned bfr(float f) {          // round-half-up bf16 bits in lo16
  return (__builtin_bit_cast(unsigned, f) + 0x8000u) >> 16;
}
__device__ inline short f2bf(float f) { return (short)bfr(f); }
__device__ inline short8 cvt8(float4 a, float4 b) {
  short8 r;
  r[0] = f2bf(a.x); r[1] = f2bf(a.y); r[2] = f2bf(a.z); r[3] = f2bf(a.w);
  r[4] = f2bf(b.x); r[5] = f2bf(b.y); r[6] = f2bf(b.z); r[7] = f2bf(b.w);
  return r;
}

__global__ __launch_bounds__(256, 3)
void hoi_fused(const float* __restrict__ X, const float* __restrict__ W1,
               const float* __restrict__ B1, const float* __restrict__ W2,
               const float* __restrict__ B2, float* __restrict__ OUT) {
  __shared__ Smem sm;
  const int tid  = threadIdx.x;
  const int lane = tid & 63, wid = tid >> 6;
  const int wr = wid >> 1, wc = wid & 1;
  const int l15 = lane & 15, g = lane >> 4;

  // XCD-grouped swizzle: the 8 n-blocks of one m-panel run consecutively on ONE XCD
  const int bid   = blockIdx.x;
  const int xcd   = bid & 7, o = bid >> 3;        // o in [0,256)
  const int m_blk = xcd * 32 + (o >> 3);          // 0..255
  const int n_blk = o & 7;                        // 0..7
  const int m0 = m_blk * 128, n0 = n_blk * 128;

  // ---- staging assignments ----
  // A: row = tid>>1 (0..127), 16 consecutive k at akc
  const int arow = tid >> 1;
  const int akc  = (tid & 1) << 4;                // 0 / 16
  const float* aptr = X + (size_t)(m0 + arow) * K1 + akc;
  // B: k-row = tid&31, col chunks 4*(tid>>5) + 32*j (float4 loads, j=0..3)
  const int bk  = tid & 31;
  const int bn0 = (tid >> 5) << 2;                // 0,4,...,28
  const float* bptr = W1 + (size_t)bk * N1 + n0 + bn0;

  // bias for this block's columns
  float b1v[4];
#pragma unroll
  for (int nt = 0; nt < 4; ++nt) b1v[nt] = B1[n0 + wc * 64 + nt * 16 + l15];

  f32x4 acc[4][4] = {};
  float4 ra[4], bq[4];

  // prologue: tile 0 into regs
#pragma unroll
  for (int q = 0; q < 4; ++q) ra[q] = *(const float4*)(aptr + 4 * q);
#pragma unroll
  for (int j = 0; j < 4; ++j) bq[j] = *(const float4*)(bptr + 32 * j);

  for (int step = 0; step < NSTEP; ++step) {
    const int cb = step & 1;

    // ---- write staged regs -> LDS[cb] (bf16) ----
    *(short8*)&sm.u.s[cb].A[arow * SAS + akc + 0] = cvt8(ra[0], ra[1]);
    *(short8*)&sm.u.s[cb].A[arow * SAS + akc + 8] = cvt8(ra[2], ra[3]);
    {
      float bb[4][4] = {{bq[0].x, bq[0].y, bq[0].z, bq[0].w},
                        {bq[1].x, bq[1].y, bq[1].z, bq[1].w},
                        {bq[2].x, bq[2].y, bq[2].z, bq[2].w},
                        {bq[3].x, bq[3].y, bq[3].z, bq[3].w}};
#pragma unroll
      for (int j = 0; j < 4; ++j)
#pragma unroll
        for (int i = 0; i < 4; ++i)
          sm.u.s[cb].BT[(bn0 + 32 * j + i) * SAS + bk] = f2bf(bb[j][i]);
    }

    // ---- prefetch next tile into regs (consumed after next barrier) ----
    if (step + 1 < NSTEP) {
      const int k0 = (step + 1) * BK;
#pragma unroll
      for (int q = 0; q < 4; ++q) ra[q] = *(const float4*)(aptr + k0 + 4 * q);
      const float* bp = bptr + (size_t)k0 * N1;
#pragma unroll
      for (int j = 0; j < 4; ++j) bq[j] = *(const float4*)(bp + 32 * j);
    }

    __syncthreads();   // tile[cb] staged; single barrier per step (dbuf)

    short8 af[4];
#pragma unroll
    for (int mt = 0; mt < 4; ++mt)
      af[mt] = *(const short8*)&sm.u.s[cb].A[(wr * 64 + mt * 16 + l15) * SAS + g * 8];
#pragma unroll
    for (int nt = 0; nt < 4; ++nt) {
      short8 bfv = *(const short8*)&sm.u.s[cb].BT[(wc * 64 + nt * 16 + l15) * SAS + g * 8];
#pragma unroll
      for (int mt = 0; mt < 4; ++mt)
        acc[mt][nt] = __builtin_amdgcn_mfma_f32_16x16x32_bf16(af[mt], bfv, acc[mt][nt], 0, 0, 0);
    }
  }

  // ---- epilogue: two 64-row phases; h/w2t alias the staging LDS ----
  for (int p = 0; p < 2; ++p) {
    __syncthreads();   // p=0: k-loop LDS reads done; p=1: phase-0 GEMM2 reads done

    if (wr == p) {     // waves owning rows p*64..p*64+63 write bias+relu h (bf16)
#pragma unroll
      for (int mt = 0; mt < 4; ++mt)
#pragma unroll
        for (int nt = 0; nt < 4; ++nt) {
          const int c = wc * 64 + nt * 16 + l15;
#pragma unroll
          for (int j = 0; j < 4; ++j) {
            const int r = mt * 16 + g * 4 + j;   // local 0..63
            sm.u.e.h[r * SHS + c] = f2bf(fmaxf(acc[mt][nt][j] + b1v[nt], 0.f));
          }
        }
    }
    if (p == 0) {      // stage w2 slice transposed: w2t[c][kk] = W2[n0+kk][c]
      const int kk = tid >> 1, ch = (tid & 1) * 32;
#pragma unroll
      for (int i = 0; i < 32; ++i) {
        const int c = ch + i;
        const float v = (c < NCOL) ? W2[(size_t)(n0 + kk) * NCOL + c] : 0.f;
        sm.u.e.w2t[c * SHS + kk] = f2bf(v);
      }
    }
    __syncthreads();   // h (and w2t) visible

    // GEMM2: 64 rows x 50 cols, K = 128; each wave takes 16 rows
    f32x4 acc2[4] = {};
#pragma unroll
    for (int ks = 0; ks < 4; ++ks) {
      const short8 a2f = *(const short8*)&sm.u.e.h[(wid * 16 + l15) * SHS + ks * 32 + g * 8];
#pragma unroll
      for (int nt2 = 0; nt2 < 4; ++nt2) {
        const short8 b2f = *(const short8*)&sm.u.e.w2t[(nt2 * 16 + l15) * SHS + ks * 32 + g * 8];
        acc2[nt2] = __builtin_amdgcn_mfma_f32_16x16x32_bf16(a2f, b2f, acc2[nt2], 0, 0, 0);
      }
    }

#pragma unroll
    for (int nt2 = 0; nt2 < 4; ++nt2) {
      const int c = nt2 * 16 + l15;
      if (c < NCOL) {
#pragma unroll
        for (int j = 0; j < 4; ++j) {
          const int r = m0 + p * 64 + wid * 16 + g * 4 + j;
          float v = acc2[nt2][j];
          if (n_blk == 0) v += B2[c];
          atomicAdd(&OUT[(size_t)r * NCOL + c], v);
        }
      }
    }
  }
}

extern "C" void kernel_launch(void* const* d_in, const int* in_sizes, int n_in,
                              void* d_out, int out_size, void* d_ws, size_t ws_size,
                              hipStream_t stream) {
  const float* X  = (const float*)d_in[0];
  const float* W1 = (const float*)d_in[1];
  const float* B1 = (const float*)d_in[2];
  const float* W2 = (const float*)d_in[3];
  const float* B2 = (const float*)d_in[4];
  float* OUT = (float*)d_out;

  hipMemsetAsync(d_out, 0, (size_t)out_size * sizeof(float), stream);
  hipLaunchKernelGGL(hoi_fused, dim3(2048), dim3(256), 0, stream, X, W1, B1, W2, B2, OUT);
}

// Round 5
// 467.178 us; speedup vs baseline: 1.3798x; 1.3798x over previous
//
#include <hip/hip_runtime.h>

#define K1 3072
#define N1 1024
#define NCOL 50
#define BK 32
#define NSTEP (K1 / BK)   // 96
#define SAS 40            // staging row stride (bf16) = 80 B
#define SHS 136           // h / w2t row stride = 272 B

typedef float  f32x4  __attribute__((ext_vector_type(4)));
typedef short  short8 __attribute__((ext_vector_type(8)));

struct __align__(16) Smem {
  union {
    struct { short A[128 * SAS]; short BT[128 * SAS]; } s[2];  // dbuf, 41 KB
    struct { short h[64 * SHS]; short w2t[64 * SHS]; } e;      // epilogue, 34.8 KB
  } u;
};  // 41 KB -> 3 blocks/CU (reg-limited to 3 anyway)

__device__ inline unsigned bfr(float f) {          // round-half-up bf16 bits in lo16
  return (__builtin_bit_cast(unsigned, f) + 0x8000u) >> 16;
}
__device__ inline short f2bf(float f) { return (short)bfr(f); }
__device__ inline short8 cvt8(float4 a, float4 b) {
  short8 r;
  r[0] = f2bf(a.x); r[1] = f2bf(a.y); r[2] = f2bf(a.z); r[3] = f2bf(a.w);
  r[4] = f2bf(b.x); r[5] = f2bf(b.y); r[6] = f2bf(b.z); r[7] = f2bf(b.w);
  return r;
}

__global__ __launch_bounds__(256, 3)
void hoi_fused(const float* __restrict__ X, const float* __restrict__ W1,
               const float* __restrict__ B1, const float* __restrict__ W2,
               const float* __restrict__ B2, float* __restrict__ OUT) {
  __shared__ Smem sm;
  const int tid  = threadIdx.x;
  const int lane = tid & 63, wid = tid >> 6;
  const int wr = wid >> 1, wc = wid & 1;
  const int l15 = lane & 15, g = lane >> 4;

  // XCD-grouped swizzle: the 8 n-blocks of one m-panel run consecutively on ONE XCD
  const int bid   = blockIdx.x;
  const int xcd   = bid & 7, o = bid >> 3;        // o in [0,256)
  const int m_blk = xcd * 32 + (o >> 3);          // 0..255
  const int n_blk = o & 7;                        // 0..7
  const int m0 = m_blk * 128, n0 = n_blk * 128;

  // ---- staging assignments (R3-proven coalescing) ----
  const int arow = tid >> 1;                      // 0..127
  const int akc  = (tid & 1) << 4;                // 0 / 16
  const float* aptr = X + (size_t)(m0 + arow) * K1 + akc;
  const int bk2 = tid >> 4;                       // 0..15 (k-pair)
  const int bcm = tid & 15;                       // 0..15
  const float* bptr = W1 + (size_t)(2 * bk2) * N1 + n0 + bcm;

  float b1v[4];
#pragma unroll
  for (int nt = 0; nt < 4; ++nt) b1v[nt] = B1[n0 + wc * 64 + nt * 16 + l15];

  f32x4 acc[4][4] = {};
  float4 ra[4];
  float  rb0[8], rb1[8];

  // prologue: issue tile-0 loads
#pragma unroll
  for (int q = 0; q < 4; ++q) ra[q] = *(const float4*)(aptr + 4 * q);
#pragma unroll
  for (int i = 0; i < 8; ++i) { rb0[i] = bptr[16 * i]; rb1[i] = bptr[N1 + 16 * i]; }

  for (int step = 0; step < NSTEP; ++step) {
    const int cb = step & 1;

    // ---- cvt tile t into staging regs (compiler waits vmcnt here, not at barrier) ----
    const short8 av0 = cvt8(ra[0], ra[1]);
    const short8 av1 = cvt8(ra[2], ra[3]);
    unsigned bpk[8];
#pragma unroll
    for (int i = 0; i < 8; ++i)
      bpk[i] = bfr(rb0[i]) |
               ((__builtin_bit_cast(unsigned, rb1[i]) + 0x8000u) & 0xFFFF0000u);

    // ---- issue tile t+1 loads: in flight across ds_write + barrier + MFMA ----
    if (step + 1 < NSTEP) {
      const int k0 = (step + 1) * BK;
#pragma unroll
      for (int q = 0; q < 4; ++q) ra[q] = *(const float4*)(aptr + k0 + 4 * q);
      const float* bp = bptr + (size_t)k0 * N1;
#pragma unroll
      for (int i = 0; i < 8; ++i) { rb0[i] = bp[16 * i]; rb1[i] = bp[N1 + 16 * i]; }
    }

    // ---- stage tile t -> LDS[cb] ----
    *(short8*)&sm.u.s[cb].A[arow * SAS + akc + 0] = av0;
    *(short8*)&sm.u.s[cb].A[arow * SAS + akc + 8] = av1;
#pragma unroll
    for (int i = 0; i < 8; ++i)
      *(unsigned*)&sm.u.s[cb].BT[(bcm + 16 * i) * SAS + 2 * bk2] = bpk[i];

    // ---- raw barrier: drain LDS writes only; global loads stay in flight ----
    asm volatile("s_waitcnt lgkmcnt(0)" ::: "memory");
    __builtin_amdgcn_s_barrier();
    __builtin_amdgcn_sched_barrier(0);   // keep frag reads below the barrier

    // ---- MFMA on LDS[cb]; writes of t+1 target LDS[cb^1] (dbuf => safe) ----
    short8 af[4];
#pragma unroll
    for (int mt = 0; mt < 4; ++mt)
      af[mt] = *(const short8*)&sm.u.s[cb].A[(wr * 64 + mt * 16 + l15) * SAS + g * 8];
#pragma unroll
    for (int nt = 0; nt < 4; ++nt) {
      short8 bfv = *(const short8*)&sm.u.s[cb].BT[(wc * 64 + nt * 16 + l15) * SAS + g * 8];
#pragma unroll
      for (int mt = 0; mt < 4; ++mt)
        acc[mt][nt] = __builtin_amdgcn_mfma_f32_16x16x32_bf16(af[mt], bfv, acc[mt][nt], 0, 0, 0);
    }
  }

  // ---- epilogue: two 64-row phases; h/w2t alias the staging LDS ----
  for (int p = 0; p < 2; ++p) {
    __syncthreads();   // p=0: k-loop LDS reads done; p=1: phase-0 GEMM2 reads done

    if (wr == p) {     // waves owning rows p*64..p*64+63 write bias+relu h (bf16)
#pragma unroll
      for (int mt = 0; mt < 4; ++mt)
#pragma unroll
        for (int nt = 0; nt < 4; ++nt) {
          const int c = wc * 64 + nt * 16 + l15;
#pragma unroll
          for (int j = 0; j < 4; ++j) {
            const int r = mt * 16 + g * 4 + j;   // local 0..63
            sm.u.e.h[r * SHS + c] = f2bf(fmaxf(acc[mt][nt][j] + b1v[nt], 0.f));
          }
        }
    }
    if (p == 0) {      // stage w2 slice transposed: w2t[c][kk] = W2[n0+kk][c]
      const int kk = tid >> 1, ch = (tid & 1) * 32;
#pragma unroll
      for (int i = 0; i < 32; ++i) {
        const int c = ch + i;
        const float v = (c < NCOL) ? W2[(size_t)(n0 + kk) * NCOL + c] : 0.f;
        sm.u.e.w2t[c * SHS + kk] = f2bf(v);
      }
    }
    __syncthreads();   // h (and w2t) visible

    // GEMM2: 64 rows x 50 cols, K = 128; each wave takes 16 rows
    f32x4 acc2[4] = {};
#pragma unroll
    for (int ks = 0; ks < 4; ++ks) {
      const short8 a2f = *(const short8*)&sm.u.e.h[(wid * 16 + l15) * SHS + ks * 32 + g * 8];
#pragma unroll
      for (int nt2 = 0; nt2 < 4; ++nt2) {
        const short8 b2f = *(const short8*)&sm.u.e.w2t[(nt2 * 16 + l15) * SHS + ks * 32 + g * 8];
        acc2[nt2] = __builtin_amdgcn_mfma_f32_16x16x32_bf16(a2f, b2f, acc2[nt2], 0, 0, 0);
      }
    }

#pragma unroll
    for (int nt2 = 0; nt2 < 4; ++nt2) {
      const int c = nt2 * 16 + l15;
      if (c < NCOL) {
#pragma unroll
        for (int j = 0; j < 4; ++j) {
          const int r = m0 + p * 64 + wid * 16 + g * 4 + j;
          float v = acc2[nt2][j];
          if (n_blk == 0) v += B2[c];
          atomicAdd(&OUT[(size_t)r * NCOL + c], v);
        }
      }
    }
  }
}

extern "C" void kernel_launch(void* const* d_in, const int* in_sizes, int n_in,
                              void* d_out, int out_size, void* d_ws, size_t ws_size,
                              hipStream_t stream) {
  const float* X  = (const float*)d_in[0];
  const float* W1 = (const float*)d_in[1];
  const float* B1 = (const float*)d_in[2];
  const float* W2 = (const float*)d_in[3];
  const float* B2 = (const float*)d_in[4];
  float* OUT = (float*)d_out;

  hipMemsetAsync(d_out, 0, (size_t)out_size * sizeof(float), stream);
  hipLaunchKernelGGL(hoi_fused, dim3(2048), dim3(256), 0, stream, X, W1, B1, W2, B2, OUT);
}